// Round 13
// baseline (952.313 us; speedup 1.0000x reference)
//
#include <hip/hip_runtime.h>

namespace {
constexpr int NB = 1024, NT = 1024, NH = 128;
constexpr float L2E = 1.4426950408889634f;

typedef __bf16 bf16x8 __attribute__((ext_vector_type(8)));
typedef float  f32x4  __attribute__((ext_vector_type(4)));
typedef int    i32x4  __attribute__((ext_vector_type(4)));
union FRAG { i32x4 i; bf16x8 b; };

__device__ __forceinline__ unsigned short bfb(float f) {   // HW RNE f32->bf16
  union { __bf16 h; unsigned short u; } c; c.h = (__bf16)f; return c.u;
}
__device__ __forceinline__ unsigned pkbf(float a, float b) {
  return (unsigned)bfb(a) | ((unsigned)bfb(b) << 16);
}
__device__ __forceinline__ unsigned long long pk4(const f32x4 v) {
  return (unsigned long long)pkbf(v[0], v[1]) |
         ((unsigned long long)pkbf(v[2], v[3]) << 32);
}
__device__ __forceinline__ float ex2(float x) { return __builtin_amdgcn_exp2f(x); }
__device__ __forceinline__ float rcp_(float x) { return __builtin_amdgcn_rcpf(x); }

// 8 consecutive floats -> bf16 fragment (k = 32s + 8lg + j map, verified r0/r1)
__device__ __forceinline__ FRAG pk8(const float* pp, float sc) {
  FRAG f;
  #pragma unroll
  for (int j = 0; j < 4; ++j)
    f.i[j] = (int)pkbf(pp[2 * j] * sc, pp[2 * j + 1] * sc);
  return f;
}
} // namespace

#define MFMA(a, b, c) __builtin_amdgcn_mfma_f32_16x16x32_bf16(a, b, c, 0, 0, 0)
// LDS-only barrier: never drains vmcnt (global h-stream / x-prefetch in flight)
#define BAR() do { \
  asm volatile("s_waitcnt lgkmcnt(0)" ::: "memory"); \
  __builtin_amdgcn_s_barrier(); \
} while (0)

// ---------------------------------------------------------------------------
// Combined kernel, grid = 512 x 512 threads.
//   blocks 0-63 (t0<NT): rnn role — r11 fragment-major body with:
//     (1) split MFMA accumulator chains (depth 5 -> 3 + f32x4 add),
//     (2) x_hat + staging hoisted BEFORE the MFMAs (fills read/MFMA latency
//         instead of extending the pre-barrier tail),
//   remaining blocks: head role — round-7 verbatim, consumes hprev chunk.
// ---------------------------------------------------------------------------
__global__ __launch_bounds__(512, 2)
void grud_combo(const float* __restrict__ x, const float* __restrict__ x_mean,
                const float* __restrict__ dxw, const float* __restrict__ dxb,
                const float* __restrict__ dhw, const float* __restrict__ dhb,
                const float* __restrict__ w_ih, const float* __restrict__ w_hh,
                const float* __restrict__ b_ih, const float* __restrict__ b_hh,
                const float* __restrict__ w1, const float* __restrict__ b1,
                const float* __restrict__ w2, const float* __restrict__ b2,
                const float* __restrict__ wu1, const float* __restrict__ bu1,
                const float* __restrict__ wu2, const float* __restrict__ bu2,
                float* __restrict__ out,
                char* __restrict__ hcur, const char* __restrict__ hprev,
                float* __restrict__ hstate, float* __restrict__ runst,
                float* __restrict__ xlst, int t0, int t0p, int Tc,
                int niter, int hb0)
{
  __shared__ __align__(16) char lds[40960];

  const int tid = threadIdx.x;
  const int lane = tid & 63, wv = tid >> 6;
  const int lr = lane & 15, lg = lane >> 4;

  if (t0 < NT && blockIdx.x < 64) {
    // =================== RNN ROLE (fragment-major LDS) ===================
    float (*xw)[16][17] = (float(*)[16][17])lds;      // 2176 B
    char* ginB = lds + 2176;                          // 2 x 1024 B fragment-major
    char* hdL  = lds + 4224;                          // 2 x 4096 B fragment-major

    const int b0 = blockIdx.x * 16;
    const int uidx = wv * 16 + lr;     // weight-row index (A operand)
    const int uu0  = wv * 16 + 4 * lg; // this lane's first owned unit (D rows)

    FRAG bhh[3][4], bgi[3];
    #pragma unroll
    for (int g = 0; g < 3; ++g) {
      const float sc = (g < 2) ? -L2E : 2.f * L2E;
      const int grow = g * 128 + uidx;
      const float* wrow = w_hh + (size_t)grow * NH;
      #pragma unroll
      for (int s = 0; s < 4; ++s) bhh[g][s] = pk8(wrow + 32 * s + 8 * lg, sc);
      FRAG f; f.i = i32x4{0, 0, 0, 0};
      if (lg < 2) {
        unsigned e[8];
        #pragma unroll
        for (int j = 0; j < 8; ++j) {
          const int c = 8 * lg + j; float v = 0.f;
          if (c < 12) {
            const int ch = c >> 1;
            v = ((c & 1) ? w_ih[(size_t)grow * 12 + 6 + ch]
                         : w_ih[(size_t)grow * 12 + ch]) * sc;
          } else if (c == 12) {
            v = ((g < 2) ? (b_ih[grow] + b_hh[grow]) : b_ih[grow]) * sc;
          }
          e[j] = bfb(v);
        }
        f.i[0] = (int)(e[0] | (e[1] << 16)); f.i[1] = (int)(e[2] | (e[3] << 16));
        f.i[2] = (int)(e[4] | (e[5] << 16)); f.i[3] = (int)(e[6] | (e[7] << 16));
      }
      bgi[g] = f;
    }
    f32x4 dhwV, dhbV, bhnV;
    #pragma unroll
    for (int r = 0; r < 4; ++r) {
      dhwV[r] = -L2E * dhw[uu0 + r];
      dhbV[r] = -L2E * dhb[uu0 + r];
      bhnV[r] = b_hh[256 + uu0 + r] * (2.f * L2E);
    }

    // x̂ lanes: waves 0-3, lanes 0..23
    const int  item = wv * 24 + lane;
    const bool xl = (wv < 4) && (lane < 24);
    const int  xrow = item / 6, xch = item - 6 * (item / 6);
    float dxwS = 0.f, dxbS = 0.f, xm_l = 0.f, run = 0.f, xlast = 0.f;
    if (xl) {
      dxwS = -L2E * dxw[xch]; dxbS = -L2E * dxb[xch]; xm_l = x_mean[xch];
      if (t0 > 0) { run = runst[(b0 + xrow) * 6 + xch]; xlast = xlst[(b0 + xrow) * 6 + xch]; }
    }
    // x̂ write offset in fragment-major gin
    const int ginWo = (((2 * xch) >> 3) << 8) + xrow * 16 + ((2 * xch) & 7) * 2;

    // stagers: waves 4-7
    const bool sl = (tid >= 256) && (tid < 464);
    const int sid = tid - 256;
    const int rrow = sid / 13, rcc = sid - 13 * (sid / 13);
    const float* xbase = x + (size_t)(b0 + rrow) * (NT * 13) + rcc;

    f32x4 hn = {0.f, 0.f, 0.f, 0.f};
    if (t0 > 0) hn = *(const f32x4*)&hstate[(size_t)(b0 + lr) * NH + uu0];

    // fragment-major offsets: read = s*1024 + lane*16 (conflict-free);
    // write = (2wv+(lg>>1))*256 + lr*16 + (lg&1)*8
    const int wOff = (2 * wv + (lg >> 1)) * 256 + lr * 16 + (lg & 1) * 8;
    const int rBase = lane * 16;

    // zero both gin parity buffers (2048 B)
    ((unsigned*)ginB)[tid] = 0u;

    const int cb0 = t0 & 1;
    if (sl) {
      xw[cb0][rrow][rcc]     = xbase[(size_t)t0 * 13];
      const int t1 = (t0 + 1 < NT) ? t0 + 1 : NT - 1;
      xw[cb0 ^ 1][rrow][rcc] = xbase[(size_t)t1 * 13];
    }
    __syncthreads();

    if (tid < 32) {   // bias column k=12 -> block 1, byte 8: {1.0bf16, 0}
      const int par = tid >> 4, row = tid & 15;
      *(unsigned*)(ginB + par * 1024 + 256 + row * 16 + 8) = 0x00003F80u;
    }

    f32x4 hd;
    {
      const float dt0 = xw[cb0][lr][12];
      #pragma unroll
      for (int r = 0; r < 4; ++r)
        hd[r] = ex2(fminf(dt0 * dhwV[r] + dhbV[r], 0.f)) * hn[r];
      *(unsigned long long*)(hdL + cb0 * 4096 + wOff) = pk4(hd);
    }
    if (xl) {
      const float xv = xw[cb0][xrow][xch], mt = xw[cb0][xrow][6 + xch];
      const float dtv = xw[cb0][xrow][12];
      const bool obs = mt > 0.5f;
      run = obs ? 0.f : run + dtv;
      const float gx = ex2(fminf(run * dxwS + dxbS, 0.f));
      xlast = obs ? xv : xlast;
      const float xh = mt * xv + (1.f - mt) * (gx * xlast + (1.f - gx) * xm_l);
      *(unsigned*)(ginB + cb0 * 1024 + ginWo) = pkbf(xh, mt);
    }
    float xr2 = 0.f;
    if (sl) { const int t2 = (t0 + 2 < NT) ? t0 + 2 : NT - 1; xr2 = xbase[(size_t)t2 * 13]; }
    BAR();

    char* hwp = hcur + (((size_t)blockIdx.x * Tc) << 12) + wv * 32 + lg * 8 + lr * 256;
    const f32x4 z4 = {0.f, 0.f, 0.f, 0.f};
    const int tend = t0 + Tc;

    #pragma unroll 1
    for (int t = t0; t < tend; ++t) {
      const int p = t & 1, q = p ^ 1;

      // gamma for t+1 hoisted (dt staged)
      const float dtn = xw[q][lr][12];
      f32x4 gmn;
      #pragma unroll
      for (int r = 0; r < 4; ++r)
        gmn[r] = ex2(fminf(dtn * dhwV[r] + dhbV[r], 0.f));

      // frag reads (issue the whole burst first)
      FRAG ag; ag.i = *(const i32x4*)(ginB + p * 1024 + rBase);
      FRAG ah[4];
      #pragma unroll
      for (int s = 0; s < 4; ++s)
        ah[s].i = *(const i32x4*)(hdL + p * 4096 + s * 1024 + rBase);

      // helper work HOISTED: fills read/MFMA latency instead of the tail
      if (xl && t + 1 < tend) {            // x̂ for t+1 -> gin[q]
        const float xv = xw[q][xrow][xch], mt = xw[q][xrow][6 + xch];
        const float dtv = xw[q][xrow][12];
        const bool obs = mt > 0.5f;
        run = obs ? 0.f : run + dtv;
        const float gx = ex2(fminf(run * dxwS + dxbS, 0.f));
        xlast = obs ? xv : xlast;
        const float xh = mt * xv + (1.f - mt) * (gx * xlast + (1.f - gx) * xm_l);
        *(unsigned*)(ginB + q * 1024 + ginWo) = pkbf(xh, mt);
      }
      if (sl) {                            // stage x[t+2] -> xw[p]; prefetch t+3
        xw[p][rrow][rcc] = xr2;
        xr2 = xbase[(size_t)((t + 3 < NT) ? t + 3 : NT - 1) * 13];
      }

      // MFMAs: split accumulator chains (depth 5 -> 3 + add)
      f32x4 ra = MFMA(bgi[0].b, ag.b, z4);
      f32x4 za = MFMA(bgi[1].b, ag.b, z4);
      f32x4 ani = MFMA(bgi[2].b, ag.b, z4);
      ra = MFMA(bhh[0][0].b, ah[0].b, ra); ra = MFMA(bhh[0][1].b, ah[1].b, ra);
      za = MFMA(bhh[1][0].b, ah[0].b, za); za = MFMA(bhh[1][1].b, ah[1].b, za);
      f32x4 rb = MFMA(bhh[0][2].b, ah[2].b, z4); rb = MFMA(bhh[0][3].b, ah[3].b, rb);
      f32x4 zb = MFMA(bhh[1][2].b, ah[2].b, z4); zb = MFMA(bhh[1][3].b, ah[3].b, zb);
      f32x4 nb1 = MFMA(bhh[2][0].b, ah[0].b, z4); nb1 = MFMA(bhh[2][1].b, ah[1].b, nb1);
      f32x4 nb2 = MFMA(bhh[2][2].b, ah[2].b, z4); nb2 = MFMA(bhh[2][3].b, ah[3].b, nb2);
      f32x4 accr = ra + rb;
      f32x4 accz = za + zb;
      f32x4 anh  = nb1 + nb2;

      // tail with paired reciprocals (20 trans/lane)
      f32x4 hbv = anh + bhnV;
      float A[4];
      #pragma unroll
      for (int r = 0; r < 4; ++r) A[r] = 1.f + ex2(accr[r]);
      const float R01 = rcp_(A[0] * A[1]);
      const float R23 = rcp_(A[2] * A[3]);
      float rr[4];
      rr[0] = A[1] * R01; rr[1] = A[0] * R01;
      rr[2] = A[3] * R23; rr[3] = A[2] * R23;

      float num[4], den[4];
      #pragma unroll
      for (int r = 0; r < 4; ++r) {
        const float na = __builtin_fmaf(rr[r], hbv[r], ani[r]);
        const float En = ex2(na);
        const float Ez = ex2(accz[r]);
        const float ep1 = En + 1.f;
        num[r] = __builtin_fmaf(hd[r], ep1, (En - 1.f) * Ez);
        den[r] = ep1 * (1.f + Ez);
      }
      const float D01 = rcp_(den[0] * den[1]);
      const float D23 = rcp_(den[2] * den[3]);
      hn[0] = num[0] * den[1] * D01; hn[1] = num[1] * den[0] * D01;
      hn[2] = num[2] * den[3] * D23; hn[3] = num[3] * den[2] * D23;

      // stream h_t (8B/lane, never drained at barrier)
      *(unsigned long long*)hwp = pk4(hn);
      hwp += 4096;

      // decay for t+1 (gamma precomputed) + fragment-major LDS write
      #pragma unroll
      for (int r = 0; r < 4; ++r) hd[r] = gmn[r] * hn[r];
      *(unsigned long long*)(hdL + q * 4096 + wOff) = pk4(hd);

      BAR();
    }

    *(f32x4*)&hstate[(size_t)(b0 + lr) * NH + uu0] = hn;
    if (xl) { runst[(b0 + xrow) * 6 + xch] = run; xlst[(b0 + xrow) * 6 + xch] = xlast; }

  } else {
    // ==================== HEAD ROLE (round-7 verbatim, dynamic base) ====================
    if (t0p < 0) return;

    const int hb = blockIdx.x - hb0;             // 0..nhb-1
    const int nhb = (int)gridDim.x - hb0;
    const int tid2 = tid & 255, half = tid >> 8; // two 4-wave halves
    const int lane2 = tid2 & 63, w4 = tid2 >> 6;
    const int lr2 = lane2 & 15, lg2 = lane2 >> 4;
    char* ldsH = lds + half * 20480;             // hs@0(8K), y1@8192(8K), u1@16384(4K)

    FRAG bw1a[4], bw1b[4], bq1[4], bw2[4], bq2[2];
    #pragma unroll
    for (int s = 0; s < 4; ++s) {
      bw1a[s] = pk8(w1 + (size_t)((2 * w4) * 16 + lr2) * 128 + 32 * s + 8 * lg2, 1.f);
      bw1b[s] = pk8(w1 + (size_t)((2 * w4 + 1) * 16 + lr2) * 128 + 32 * s + 8 * lg2, 1.f);
      bq1[s]  = pk8(wu1 + (size_t)(w4 * 16 + lr2) * 128 + 32 * s + 8 * lg2, 1.f);
      if (lr2 < 6) bw2[s] = pk8(w2 + (size_t)lr2 * 128 + 32 * s + 8 * lg2, 1.f);
      else         bw2[s].i = i32x4{0, 0, 0, 0};
      if (s < 2) {
        if (lr2 < 6) bq2[s] = pk8(wu2 + (size_t)lr2 * 64 + 32 * s + 8 * lg2, 1.f);
        else         bq2[s].i = i32x4{0, 0, 0, 0};
      }
    }
    const float b1a = b1[(2 * w4) * 16 + lr2], b1b = b1[(2 * w4 + 1) * 16 + lr2];
    const float bu1l = bu1[w4 * 16 + lr2];
    const float b2l = (lr2 < 6) ? b2[lr2] : 0.f, bu2l = (lr2 < 6) ? bu2[lr2] : 0.f;
    const f32x4 z4 = {0.f, 0.f, 0.f, 0.f};

    const int tc2 = Tc >> 1, total = 64 * tc2;
    const int cy0 = (2 * w4) * 16 + lr2, cy1 = (2 * w4 + 1) * 16 + lr2;
    const int cu = w4 * 16 + lr2;

    #pragma unroll 1
    for (int it = 0; it < niter; ++it) {
      const int hu = it * (nhb * 2) + hb * 2 + half;
      const bool valid = hu < total;
      int chain = 0, tp = 0;
      if (valid) { chain = hu / tc2; tp = hu - chain * tc2; }

      if (valid) {   // stage 2 h tiles, cell-swizzled
        const char* src = hprev + (((size_t)chain * Tc + tp * 2) << 12);
        const int o = tid2 * 16, row = o >> 8, cell = (o >> 4) & 15;
        #pragma unroll
        for (int k2 = 0; k2 < 2; ++k2) {
          uint4 v = *(const uint4*)(src + k2 * 4096 + o);
          *(uint4*)(ldsH + k2 * 4096 + row * 256 + ((cell ^ (row & 7)) << 4)) = v;
        }
      }
      __syncthreads();

      if (valid) {   // layer 1 over 2 t-tiles
        #pragma unroll
        for (int k = 0; k < 2; ++k) {
          FRAG A[4];
          #pragma unroll
          for (int s = 0; s < 4; ++s)
            A[s].i = *(const i32x4*)(ldsH + k * 4096 + lr2 * 256 +
                                     (((4 * s + lg2) ^ (lr2 & 7)) << 4));
          f32x4 aa = z4, ab = z4, au = z4;
          #pragma unroll
          for (int s = 0; s < 4; ++s) {
            aa = MFMA(A[s].b, bw1a[s].b, aa);
            ab = MFMA(A[s].b, bw1b[s].b, ab);
            au = MFMA(A[s].b, bq1[s].b, au);
          }
          #pragma unroll
          for (int r = 0; r < 4; ++r) {
            const int m = k * 16 + 4 * lg2 + r;
            *(unsigned short*)(ldsH + 8192 + m * 256 + (((cy0 >> 3) ^ (m & 7)) << 4) +
                               (cy0 & 7) * 2) = bfb(fmaxf(aa[r] + b1a, 0.f));
            *(unsigned short*)(ldsH + 8192 + m * 256 + (((cy1 >> 3) ^ (m & 7)) << 4) +
                               (cy1 & 7) * 2) = bfb(fmaxf(ab[r] + b1b, 0.f));
            *(unsigned short*)(ldsH + 16384 + m * 128 + (((cu >> 3) ^ (m & 7)) << 4) +
                               (cu & 7) * 2) = bfb(fmaxf(au[r] + bu1l, 0.f));
          }
        }
      }
      __syncthreads();

      if (valid && w4 < 2) {   // layer 2: wave w4 finishes t-tile w4
        const int mrow = w4 * 16 + lr2;
        FRAG Y[4], U[2];
        #pragma unroll
        for (int s = 0; s < 4; ++s)
          Y[s].i = *(const i32x4*)(ldsH + 8192 + mrow * 256 +
                                   (((4 * s + lg2) ^ (lr2 & 7)) << 4));
        #pragma unroll
        for (int s = 0; s < 2; ++s)
          U[s].i = *(const i32x4*)(ldsH + 16384 + mrow * 128 +
                                   (((4 * s + lg2) ^ (lr2 & 7)) << 4));
        f32x4 ap = z4, aq = z4;
        #pragma unroll
        for (int s = 0; s < 4; ++s) ap = MFMA(Y[s].b, bw2[s].b, ap);
        #pragma unroll
        for (int s = 0; s < 2; ++s) aq = MFMA(U[s].b, bq2[s].b, aq);

        if (lr2 < 6) {
          const int t = t0p + tp * 2 + w4;
          #pragma unroll
          for (int r = 0; r < 4; ++r) {
            const int b = chain * 16 + 4 * lg2 + r;
            const size_t o = ((size_t)b * NT + t) * 6 + lr2;
            out[o] = ap[r] + b2l;
            const float xa = aq[r] + bu2l;
            const float sp = fmaxf(xa, 0.f) + 0.6931471805599453f *
                __builtin_amdgcn_logf(1.f + ex2(-fabsf(xa) * L2E));
            out[(size_t)NB * NT * 6 + o] = sp;
          }
        }
      }
      __syncthreads();
    }
  }
}

extern "C" void kernel_launch(void* const* d_in, const int* in_sizes, int n_in,
                              void* d_out, int out_size, void* d_ws, size_t ws_size,
                              hipStream_t stream) {
  (void)in_sizes; (void)n_in; (void)out_size;
  const float* p[18];
  for (int i = 0; i < 18; ++i) p[i] = (const float*)d_in[i];

  const size_t STATE = (size_t)1024 * 128 * 4 + 2 * (size_t)1024 * 6 * 4;
  int Tc = 512;   // fewer dispatch boundaries; adaptive down if ws too small
  while (Tc > 16 && (2 * ((size_t)Tc << 18) + STATE) > ws_size) Tc >>= 1;

  char* h0 = (char*)d_ws;
  char* h1 = h0 + ((size_t)Tc << 18);
  float* hstate = (float*)(h1 + ((size_t)Tc << 18));
  float* runst = hstate + 1024 * 128;
  float* xlst = runst + 1024 * 6;

  const int nch = NT / Tc;
  const int total = 64 * (Tc / 2);

  for (int k = 0; k <= nch; ++k) {
    char* hcur = (k & 1) ? h1 : h0;
    const char* hprev = (k & 1) ? h0 : h1;
    const int t0 = k * Tc;
    const int hb0 = (t0 < NT) ? 64 : 0;
    const int stride = (512 - hb0) * 2;
    const int niter = (total + stride - 1) / stride;
    hipLaunchKernelGGL(grud_combo, dim3(512), dim3(512), 0, stream,
                       p[0], p[1], p[2], p[3], p[4], p[5], p[6], p[7], p[8], p[9],
                       p[10], p[11], p[12], p[13], p[14], p[15], p[16], p[17],
                       (float*)d_out, hcur, hprev, hstate, runst, xlst,
                       t0, (k - 1) * Tc, Tc, niter, hb0);
  }
}

// Round 14
// 860.791 us; speedup vs baseline: 1.1063x; 1.1063x over previous
//
#include <hip/hip_runtime.h>

namespace {
constexpr int NB = 1024, NT = 1024, NH = 128;
constexpr float L2E = 1.4426950408889634f;

typedef __bf16 bf16x8 __attribute__((ext_vector_type(8)));
typedef float  f32x4  __attribute__((ext_vector_type(4)));
typedef int    i32x4  __attribute__((ext_vector_type(4)));
union FRAG { i32x4 i; bf16x8 b; };

__device__ __forceinline__ unsigned short bfb(float f) {   // HW RNE f32->bf16
  union { __bf16 h; unsigned short u; } c; c.h = (__bf16)f; return c.u;
}
__device__ __forceinline__ unsigned pkbf(float a, float b) {
  return (unsigned)bfb(a) | ((unsigned)bfb(b) << 16);
}
__device__ __forceinline__ unsigned long long pk4(const f32x4 v) {
  return (unsigned long long)pkbf(v[0], v[1]) |
         ((unsigned long long)pkbf(v[2], v[3]) << 32);
}
__device__ __forceinline__ float ex2(float x) { return __builtin_amdgcn_exp2f(x); }
__device__ __forceinline__ float rcp_(float x) { return __builtin_amdgcn_rcpf(x); }

// 8 consecutive floats -> bf16 fragment (k = 32s + 8lg + j map, verified r0/r1)
__device__ __forceinline__ FRAG pk8(const float* pp, float sc) {
  FRAG f;
  #pragma unroll
  for (int j = 0; j < 4; ++j)
    f.i[j] = (int)pkbf(pp[2 * j] * sc, pp[2 * j + 1] * sc);
  return f;
}
} // namespace

#define MFMA(a, b, c) __builtin_amdgcn_mfma_f32_16x16x32_bf16(a, b, c, 0, 0, 0)
// LDS-only barrier: never drains vmcnt (global h-stream / x-prefetch in flight)
#define BAR() do { \
  asm volatile("s_waitcnt lgkmcnt(0)" ::: "memory"); \
  __builtin_amdgcn_s_barrier(); \
} while (0)

// ---------------------------------------------------------------------------
// Combined kernel, grid = 512 x 768 threads (2 blocks/CU).
//   blocks 0-63 (t0<NT): rnn role, 12 waves:
//     waves 0-7: PURE gate waves — r11 verified body (fragment-major LDS,
//       serial MFMA chains, paired-rcp tail, gamma hoist), NO helper work.
//     waves 8-11 (tid>=512): helpers — x_hat (96 lanes) + x stagers
//       (104 lanes x 2 items). Off the gate critical path entirely.
//   remaining blocks: head role — round-7 body, THREE 4-wave halves/block.
// ---------------------------------------------------------------------------
__global__ __launch_bounds__(768, 2)
void grud_combo(const float* __restrict__ x, const float* __restrict__ x_mean,
                const float* __restrict__ dxw, const float* __restrict__ dxb,
                const float* __restrict__ dhw, const float* __restrict__ dhb,
                const float* __restrict__ w_ih, const float* __restrict__ w_hh,
                const float* __restrict__ b_ih, const float* __restrict__ b_hh,
                const float* __restrict__ w1, const float* __restrict__ b1,
                const float* __restrict__ w2, const float* __restrict__ b2,
                const float* __restrict__ wu1, const float* __restrict__ bu1,
                const float* __restrict__ wu2, const float* __restrict__ bu2,
                float* __restrict__ out,
                char* __restrict__ hcur, const char* __restrict__ hprev,
                float* __restrict__ hstate, float* __restrict__ runst,
                float* __restrict__ xlst, int t0, int t0p, int Tc,
                int niter, int hb0)
{
  __shared__ __align__(16) char lds[61440];

  const int tid = threadIdx.x;
  const int lane = tid & 63, wv = tid >> 6;
  const int lr = lane & 15, lg = lane >> 4;

  if (t0 < NT && blockIdx.x < 64) {
    // =================== RNN ROLE ===================
    float (*xw)[16][17] = (float(*)[16][17])lds;      // 2176 B
    char* ginB = lds + 2176;                          // 2 x 1024 B fragment-major
    char* hdL  = lds + 4224;                          // 2 x 4096 B fragment-major

    const int b0 = blockIdx.x * 16;
    const bool gw = tid < 512;          // gate waves 0-7
    const int uidx = (wv & 7) * 16 + lr;
    const int uu0  = (wv & 7) * 16 + 4 * lg;

    // ---- gate-wave weight fragments ----
    FRAG bhh[3][4], bgi[3];
    f32x4 dhwV = {0.f,0.f,0.f,0.f}, dhbV = {0.f,0.f,0.f,0.f}, bhnV = {0.f,0.f,0.f,0.f};
    if (gw) {
      #pragma unroll
      for (int g = 0; g < 3; ++g) {
        const float sc = (g < 2) ? -L2E : 2.f * L2E;
        const int grow = g * 128 + uidx;
        const float* wrow = w_hh + (size_t)grow * NH;
        #pragma unroll
        for (int s = 0; s < 4; ++s) bhh[g][s] = pk8(wrow + 32 * s + 8 * lg, sc);
        FRAG f; f.i = i32x4{0, 0, 0, 0};
        if (lg < 2) {
          unsigned e[8];
          #pragma unroll
          for (int j = 0; j < 8; ++j) {
            const int c = 8 * lg + j; float v = 0.f;
            if (c < 12) {
              const int ch = c >> 1;
              v = ((c & 1) ? w_ih[(size_t)grow * 12 + 6 + ch]
                           : w_ih[(size_t)grow * 12 + ch]) * sc;
            } else if (c == 12) {
              v = ((g < 2) ? (b_ih[grow] + b_hh[grow]) : b_ih[grow]) * sc;
            }
            e[j] = bfb(v);
          }
          f.i[0] = (int)(e[0] | (e[1] << 16)); f.i[1] = (int)(e[2] | (e[3] << 16));
          f.i[2] = (int)(e[4] | (e[5] << 16)); f.i[3] = (int)(e[6] | (e[7] << 16));
        }
        bgi[g] = f;
      }
      #pragma unroll
      for (int r = 0; r < 4; ++r) {
        dhwV[r] = -L2E * dhw[uu0 + r];
        dhbV[r] = -L2E * dhb[uu0 + r];
        bhnV[r] = b_hh[256 + uu0 + r] * (2.f * L2E);
      }
    }

    // ---- helpers: tid 512..767 ----
    const int hid = tid - 512;
    const bool xl = (hid >= 0) && (hid < 96);        // x_hat lanes
    const int xrow = (hid >= 0) ? hid / 6 : 0, xch = (hid >= 0) ? hid - 6 * (hid / 6) : 0;
    float dxwS = 0.f, dxbS = 0.f, xm_l = 0.f, run = 0.f, xlast = 0.f;
    if (xl) {
      dxwS = -L2E * dxw[xch]; dxbS = -L2E * dxb[xch]; xm_l = x_mean[xch];
      if (t0 > 0) { run = runst[(b0 + xrow) * 6 + xch]; xlast = xlst[(b0 + xrow) * 6 + xch]; }
    }
    const int ginWo = (((2 * xch) >> 3) << 8) + xrow * 16 + ((2 * xch) & 7) * 2;

    const bool st_ = (hid >= 96) && (hid < 200);     // stagers, 2 items each
    const int sid = (hid >= 96) ? hid - 96 : 0;      // 0..103
    const int r1r = sid / 13, r1c = sid - 13 * r1r;
    const int r2r = (sid + 104) / 13, r2c = (sid + 104) - 13 * ((sid + 104) / 13);
    const float* xb1 = x + (size_t)(b0 + r1r) * (NT * 13) + r1c;
    const float* xb2 = x + (size_t)(b0 + r2r) * (NT * 13) + r2c;

    // ---- h state (gate waves) ----
    f32x4 hn = {0.f, 0.f, 0.f, 0.f};
    if (gw && t0 > 0) hn = *(const f32x4*)&hstate[(size_t)(b0 + lr) * NH + uu0];

    // fragment-major offsets
    const int wOff = (2 * (wv & 7) + (lg >> 1)) * 256 + lr * 16 + (lg & 1) * 8;
    const int rBase = lane * 16;

    // zero both gin parity buffers (2048 B)
    if (tid < 512) ((unsigned*)ginB)[tid] = 0u;

    const int cb0 = t0 & 1;
    if (st_) {
      const int t1 = (t0 + 1 < NT) ? t0 + 1 : NT - 1;
      xw[cb0][r1r][r1c]     = xb1[(size_t)t0 * 13];
      xw[cb0 ^ 1][r1r][r1c] = xb1[(size_t)t1 * 13];
      xw[cb0][r2r][r2c]     = xb2[(size_t)t0 * 13];
      xw[cb0 ^ 1][r2r][r2c] = xb2[(size_t)t1 * 13];
    }
    __syncthreads();

    if (tid < 32) {   // bias column k=12 -> block 1, byte 8: {1.0bf16, 0}
      const int par = tid >> 4, row = tid & 15;
      *(unsigned*)(ginB + par * 1024 + 256 + row * 16 + 8) = 0x00003F80u;
    }

    f32x4 hd = {0.f, 0.f, 0.f, 0.f};
    if (gw) {
      const float dt0 = xw[cb0][lr][12];
      #pragma unroll
      for (int r = 0; r < 4; ++r)
        hd[r] = ex2(fminf(dt0 * dhwV[r] + dhbV[r], 0.f)) * hn[r];
      *(unsigned long long*)(hdL + cb0 * 4096 + wOff) = pk4(hd);
    }
    if (xl) {
      const float xv = xw[cb0][xrow][xch], mt = xw[cb0][xrow][6 + xch];
      const float dtv = xw[cb0][xrow][12];
      const bool obs = mt > 0.5f;
      run = obs ? 0.f : run + dtv;
      const float gx = ex2(fminf(run * dxwS + dxbS, 0.f));
      xlast = obs ? xv : xlast;
      const float xh = mt * xv + (1.f - mt) * (gx * xlast + (1.f - gx) * xm_l);
      *(unsigned*)(ginB + cb0 * 1024 + ginWo) = pkbf(xh, mt);
    }
    float xr2a = 0.f, xr2b = 0.f;
    if (st_) {
      const int t2 = (t0 + 2 < NT) ? t0 + 2 : NT - 1;
      xr2a = xb1[(size_t)t2 * 13]; xr2b = xb2[(size_t)t2 * 13];
    }
    BAR();

    char* hwp = hcur + (((size_t)blockIdx.x * Tc) << 12) + (wv & 7) * 32 + lg * 8 + lr * 256;
    const f32x4 z4 = {0.f, 0.f, 0.f, 0.f};
    const int tend = t0 + Tc;

    #pragma unroll 1
    for (int t = t0; t < tend; ++t) {
      const int p = t & 1, q = p ^ 1;

      if (gw) {
        // ---- pure gate path (r11 verbatim) ----
        const float dtn = xw[q][lr][12];
        f32x4 gmn;
        #pragma unroll
        for (int r = 0; r < 4; ++r)
          gmn[r] = ex2(fminf(dtn * dhwV[r] + dhbV[r], 0.f));

        FRAG ag; ag.i = *(const i32x4*)(ginB + p * 1024 + rBase);
        FRAG ah[4];
        #pragma unroll
        for (int s = 0; s < 4; ++s)
          ah[s].i = *(const i32x4*)(hdL + p * 4096 + s * 1024 + rBase);

        f32x4 accr = MFMA(bgi[0].b, ag.b, z4);
        f32x4 accz = MFMA(bgi[1].b, ag.b, z4);
        f32x4 ani  = MFMA(bgi[2].b, ag.b, z4);
        f32x4 anh  = z4;
        #pragma unroll
        for (int s = 0; s < 4; ++s) {
          accr = MFMA(bhh[0][s].b, ah[s].b, accr);
          accz = MFMA(bhh[1][s].b, ah[s].b, accz);
          anh  = MFMA(bhh[2][s].b, ah[s].b, anh);
        }

        // paired-rcp tail (20 trans/lane)
        f32x4 hbv = anh + bhnV;
        float A[4];
        #pragma unroll
        for (int r = 0; r < 4; ++r) A[r] = 1.f + ex2(accr[r]);
        const float R01 = rcp_(A[0] * A[1]);
        const float R23 = rcp_(A[2] * A[3]);
        float rr[4];
        rr[0] = A[1] * R01; rr[1] = A[0] * R01;
        rr[2] = A[3] * R23; rr[3] = A[2] * R23;

        float num[4], den[4];
        #pragma unroll
        for (int r = 0; r < 4; ++r) {
          const float na = __builtin_fmaf(rr[r], hbv[r], ani[r]);
          const float En = ex2(na);
          const float Ez = ex2(accz[r]);
          const float ep1 = En + 1.f;
          num[r] = __builtin_fmaf(hd[r], ep1, (En - 1.f) * Ez);
          den[r] = ep1 * (1.f + Ez);
        }
        const float D01 = rcp_(den[0] * den[1]);
        const float D23 = rcp_(den[2] * den[3]);
        hn[0] = num[0] * den[1] * D01; hn[1] = num[1] * den[0] * D01;
        hn[2] = num[2] * den[3] * D23; hn[3] = num[3] * den[2] * D23;

        // stream h_t (8B/lane, never drained at barrier)
        *(unsigned long long*)hwp = pk4(hn);

        // decay for t+1 (gamma precomputed) + fragment-major LDS write
        #pragma unroll
        for (int r = 0; r < 4; ++r) hd[r] = gmn[r] * hn[r];
        *(unsigned long long*)(hdL + q * 4096 + wOff) = pk4(hd);
      } else {
        // ---- helper waves: x_hat(t+1) + stage x[t+2] ----
        if (xl && t + 1 < tend) {
          const float xv = xw[q][xrow][xch], mt = xw[q][xrow][6 + xch];
          const float dtv = xw[q][xrow][12];
          const bool obs = mt > 0.5f;
          run = obs ? 0.f : run + dtv;
          const float gx = ex2(fminf(run * dxwS + dxbS, 0.f));
          xlast = obs ? xv : xlast;
          const float xh = mt * xv + (1.f - mt) * (gx * xlast + (1.f - gx) * xm_l);
          *(unsigned*)(ginB + q * 1024 + ginWo) = pkbf(xh, mt);
        }
        if (st_) {
          const int t3 = (t + 3 < NT) ? t + 3 : NT - 1;
          xw[p][r1r][r1c] = xr2a; xr2a = xb1[(size_t)t3 * 13];
          xw[p][r2r][r2c] = xr2b; xr2b = xb2[(size_t)t3 * 13];
        }
      }
      hwp += 4096;
      BAR();
    }

    // ---- carry state ----
    if (gw) *(f32x4*)&hstate[(size_t)(b0 + lr) * NH + uu0] = hn;
    if (xl) { runst[(b0 + xrow) * 6 + xch] = run; xlst[(b0 + xrow) * 6 + xch] = xlast; }

  } else {
    // ========== HEAD ROLE (round-7 body, THREE 4-wave halves) ==========
    if (t0p < 0) return;

    const int hb = blockIdx.x - hb0;             // 0..nhb-1
    const int nhb = (int)gridDim.x - hb0;
    const int tid2 = tid & 255, half = tid >> 8; // three 4-wave halves (0,1,2)
    const int lane2 = tid2 & 63, w4 = tid2 >> 6;
    const int lr2 = lane2 & 15, lg2 = lane2 >> 4;
    char* ldsH = lds + half * 20480;             // hs@0(8K), y1@8192(8K), u1@16384(4K)

    FRAG bw1a[4], bw1b[4], bq1[4], bw2[4], bq2[2];
    #pragma unroll
    for (int s = 0; s < 4; ++s) {
      bw1a[s] = pk8(w1 + (size_t)((2 * w4) * 16 + lr2) * 128 + 32 * s + 8 * lg2, 1.f);
      bw1b[s] = pk8(w1 + (size_t)((2 * w4 + 1) * 16 + lr2) * 128 + 32 * s + 8 * lg2, 1.f);
      bq1[s]  = pk8(wu1 + (size_t)(w4 * 16 + lr2) * 128 + 32 * s + 8 * lg2, 1.f);
      if (lr2 < 6) bw2[s] = pk8(w2 + (size_t)lr2 * 128 + 32 * s + 8 * lg2, 1.f);
      else         bw2[s].i = i32x4{0, 0, 0, 0};
      if (s < 2) {
        if (lr2 < 6) bq2[s] = pk8(wu2 + (size_t)lr2 * 64 + 32 * s + 8 * lg2, 1.f);
        else         bq2[s].i = i32x4{0, 0, 0, 0};
      }
    }
    const float b1a = b1[(2 * w4) * 16 + lr2], b1b = b1[(2 * w4 + 1) * 16 + lr2];
    const float bu1l = bu1[w4 * 16 + lr2];
    const float b2l = (lr2 < 6) ? b2[lr2] : 0.f, bu2l = (lr2 < 6) ? bu2[lr2] : 0.f;
    const f32x4 z4 = {0.f, 0.f, 0.f, 0.f};

    const int tc2 = Tc >> 1, total = 64 * tc2;
    const int cy0 = (2 * w4) * 16 + lr2, cy1 = (2 * w4 + 1) * 16 + lr2;
    const int cu = w4 * 16 + lr2;

    #pragma unroll 1
    for (int it = 0; it < niter; ++it) {
      const int hu = it * (nhb * 3) + hb * 3 + half;
      const bool valid = hu < total;
      int chain = 0, tp = 0;
      if (valid) { chain = hu / tc2; tp = hu - chain * tc2; }

      if (valid) {   // stage 2 h tiles, cell-swizzled
        const char* src = hprev + (((size_t)chain * Tc + tp * 2) << 12);
        const int o = tid2 * 16, row = o >> 8, cell = (o >> 4) & 15;
        #pragma unroll
        for (int k2 = 0; k2 < 2; ++k2) {
          uint4 v = *(const uint4*)(src + k2 * 4096 + o);
          *(uint4*)(ldsH + k2 * 4096 + row * 256 + ((cell ^ (row & 7)) << 4)) = v;
        }
      }
      __syncthreads();

      if (valid) {   // layer 1 over 2 t-tiles
        #pragma unroll
        for (int k = 0; k < 2; ++k) {
          FRAG A[4];
          #pragma unroll
          for (int s = 0; s < 4; ++s)
            A[s].i = *(const i32x4*)(ldsH + k * 4096 + lr2 * 256 +
                                     (((4 * s + lg2) ^ (lr2 & 7)) << 4));
          f32x4 aa = z4, ab = z4, au = z4;
          #pragma unroll
          for (int s = 0; s < 4; ++s) {
            aa = MFMA(A[s].b, bw1a[s].b, aa);
            ab = MFMA(A[s].b, bw1b[s].b, ab);
            au = MFMA(A[s].b, bq1[s].b, au);
          }
          #pragma unroll
          for (int r = 0; r < 4; ++r) {
            const int m = k * 16 + 4 * lg2 + r;
            *(unsigned short*)(ldsH + 8192 + m * 256 + (((cy0 >> 3) ^ (m & 7)) << 4) +
                               (cy0 & 7) * 2) = bfb(fmaxf(aa[r] + b1a, 0.f));
            *(unsigned short*)(ldsH + 8192 + m * 256 + (((cy1 >> 3) ^ (m & 7)) << 4) +
                               (cy1 & 7) * 2) = bfb(fmaxf(ab[r] + b1b, 0.f));
            *(unsigned short*)(ldsH + 16384 + m * 128 + (((cu >> 3) ^ (m & 7)) << 4) +
                               (cu & 7) * 2) = bfb(fmaxf(au[r] + bu1l, 0.f));
          }
        }
      }
      __syncthreads();

      if (valid && w4 < 2) {   // layer 2: wave w4 finishes t-tile w4
        const int mrow = w4 * 16 + lr2;
        FRAG Y[4], U[2];
        #pragma unroll
        for (int s = 0; s < 4; ++s)
          Y[s].i = *(const i32x4*)(ldsH + 8192 + mrow * 256 +
                                   (((4 * s + lg2) ^ (lr2 & 7)) << 4));
        #pragma unroll
        for (int s = 0; s < 2; ++s)
          U[s].i = *(const i32x4*)(ldsH + 16384 + mrow * 128 +
                                   (((4 * s + lg2) ^ (lr2 & 7)) << 4));
        f32x4 ap = z4, aq = z4;
        #pragma unroll
        for (int s = 0; s < 4; ++s) ap = MFMA(Y[s].b, bw2[s].b, ap);
        #pragma unroll
        for (int s = 0; s < 2; ++s) aq = MFMA(U[s].b, bq2[s].b, aq);

        if (lr2 < 6) {
          const int t = t0p + tp * 2 + w4;
          #pragma unroll
          for (int r = 0; r < 4; ++r) {
            const int b = chain * 16 + 4 * lg2 + r;
            const size_t o = ((size_t)b * NT + t) * 6 + lr2;
            out[o] = ap[r] + b2l;
            const float xa = aq[r] + bu2l;
            const float sp = fmaxf(xa, 0.f) + 0.6931471805599453f *
                __builtin_amdgcn_logf(1.f + ex2(-fabsf(xa) * L2E));
            out[(size_t)NB * NT * 6 + o] = sp;
          }
        }
      }
      __syncthreads();
    }
  }
}

extern "C" void kernel_launch(void* const* d_in, const int* in_sizes, int n_in,
                              void* d_out, int out_size, void* d_ws, size_t ws_size,
                              hipStream_t stream) {
  (void)in_sizes; (void)n_in; (void)out_size;
  const float* p[18];
  for (int i = 0; i < 18; ++i) p[i] = (const float*)d_in[i];

  const size_t STATE = (size_t)1024 * 128 * 4 + 2 * (size_t)1024 * 6 * 4;
  int Tc = 256;   // small head-tail dispatch; hws dbuf fits ws
  while (Tc > 16 && (2 * ((size_t)Tc << 18) + STATE) > ws_size) Tc >>= 1;

  char* h0 = (char*)d_ws;
  char* h1 = h0 + ((size_t)Tc << 18);
  float* hstate = (float*)(h1 + ((size_t)Tc << 18));
  float* runst = hstate + 1024 * 128;
  float* xlst = runst + 1024 * 6;

  const int nch = NT / Tc;
  const int total = 64 * (Tc / 2);

  for (int k = 0; k <= nch; ++k) {
    char* hcur = (k & 1) ? h1 : h0;
    const char* hprev = (k & 1) ? h0 : h1;
    const int t0 = k * Tc;
    const int hb0 = (t0 < NT) ? 64 : 0;
    const int stride = (512 - hb0) * 3;
    const int niter = (total + stride - 1) / stride;
    hipLaunchKernelGGL(grud_combo, dim3(512), dim3(768), 0, stream,
                       p[0], p[1], p[2], p[3], p[4], p[5], p[6], p[7], p[8], p[9],
                       p[10], p[11], p[12], p[13], p[14], p[15], p[16], p[17],
                       (float*)d_out, hcur, hprev, hstate, runst, xlst,
                       t0, (k - 1) * Tc, Tc, niter, hb0);
  }
}

// Round 15
// 820.602 us; speedup vs baseline: 1.1605x; 1.0490x over previous
//
#include <hip/hip_runtime.h>

namespace {
constexpr int NB = 1024, NT = 1024, NH = 128;
constexpr float L2E = 1.4426950408889634f;

typedef __bf16 bf16x8 __attribute__((ext_vector_type(8)));
typedef float  f32x4  __attribute__((ext_vector_type(4)));
typedef int    i32x4  __attribute__((ext_vector_type(4)));
union FRAG { i32x4 i; bf16x8 b; };

__device__ __forceinline__ unsigned short bfb(float f) {   // HW RNE f32->bf16
  union { __bf16 h; unsigned short u; } c; c.h = (__bf16)f; return c.u;
}
__device__ __forceinline__ unsigned pkbf(float a, float b) {
  return (unsigned)bfb(a) | ((unsigned)bfb(b) << 16);
}
__device__ __forceinline__ unsigned long long pk4(const f32x4 v) {
  return (unsigned long long)pkbf(v[0], v[1]) |
         ((unsigned long long)pkbf(v[2], v[3]) << 32);
}
__device__ __forceinline__ float ex2(float x) { return __builtin_amdgcn_exp2f(x); }
__device__ __forceinline__ float rcp_(float x) { return __builtin_amdgcn_rcpf(x); }

// 8 consecutive floats -> bf16 fragment (k = 32s + 8lg + j map, verified r0/r1)
__device__ __forceinline__ FRAG pk8(const float* pp, float sc) {
  FRAG f;
  #pragma unroll
  for (int j = 0; j < 4; ++j)
    f.i[j] = (int)pkbf(pp[2 * j] * sc, pp[2 * j + 1] * sc);
  return f;
}
} // namespace

#define MFMA(a, b, c) __builtin_amdgcn_mfma_f32_16x16x32_bf16(a, b, c, 0, 0, 0)
// LDS-only barrier: never drains vmcnt (global h-stream / x-prefetch in flight)
#define BAR() do { \
  asm volatile("s_waitcnt lgkmcnt(0)" ::: "memory"); \
  __builtin_amdgcn_s_barrier(); \
} while (0)

// ---------------------------------------------------------------------------
// Combined kernel, grid = 256 x 512 threads (1 block/CU).
//   SINGLE CHANGE vs r11 (827us best): grid 512 -> 256 so each rnn block gets
//   a DEDICATED CU — no co-tenant head block competing for the LDS pipe
//   (rnn gate waves need ~480cy/step of ds_read_b128; r11 shared that pipe
//   with a head block's staging/frag traffic).
//   blocks 0-63 (t0<NT): rnn role — r11 fragment-major body verbatim.
//   remaining blocks: head role — round-7 verbatim, consumes hprev chunk.
// ---------------------------------------------------------------------------
__global__ __launch_bounds__(512, 2)
void grud_combo(const float* __restrict__ x, const float* __restrict__ x_mean,
                const float* __restrict__ dxw, const float* __restrict__ dxb,
                const float* __restrict__ dhw, const float* __restrict__ dhb,
                const float* __restrict__ w_ih, const float* __restrict__ w_hh,
                const float* __restrict__ b_ih, const float* __restrict__ b_hh,
                const float* __restrict__ w1, const float* __restrict__ b1,
                const float* __restrict__ w2, const float* __restrict__ b2,
                const float* __restrict__ wu1, const float* __restrict__ bu1,
                const float* __restrict__ wu2, const float* __restrict__ bu2,
                float* __restrict__ out,
                char* __restrict__ hcur, const char* __restrict__ hprev,
                float* __restrict__ hstate, float* __restrict__ runst,
                float* __restrict__ xlst, int t0, int t0p, int Tc,
                int niter, int hb0)
{
  __shared__ __align__(16) char lds[40960];

  const int tid = threadIdx.x;
  const int lane = tid & 63, wv = tid >> 6;
  const int lr = lane & 15, lg = lane >> 4;

  if (t0 < NT && blockIdx.x < 64) {
    // =================== RNN ROLE (fragment-major LDS, r11 verbatim) ===================
    float (*xw)[16][17] = (float(*)[16][17])lds;      // 2176 B
    char* ginB = lds + 2176;                          // 2 x 1024 B fragment-major
    char* hdL  = lds + 4224;                          // 2 x 4096 B fragment-major

    const int b0 = blockIdx.x * 16;
    const int uidx = wv * 16 + lr;     // weight-row index (A operand)
    const int uu0  = wv * 16 + 4 * lg; // this lane's first owned unit (D rows)

    FRAG bhh[3][4], bgi[3];
    #pragma unroll
    for (int g = 0; g < 3; ++g) {
      const float sc = (g < 2) ? -L2E : 2.f * L2E;
      const int grow = g * 128 + uidx;
      const float* wrow = w_hh + (size_t)grow * NH;
      #pragma unroll
      for (int s = 0; s < 4; ++s) bhh[g][s] = pk8(wrow + 32 * s + 8 * lg, sc);
      FRAG f; f.i = i32x4{0, 0, 0, 0};
      if (lg < 2) {
        unsigned e[8];
        #pragma unroll
        for (int j = 0; j < 8; ++j) {
          const int c = 8 * lg + j; float v = 0.f;
          if (c < 12) {
            const int ch = c >> 1;
            v = ((c & 1) ? w_ih[(size_t)grow * 12 + 6 + ch]
                         : w_ih[(size_t)grow * 12 + ch]) * sc;
          } else if (c == 12) {
            v = ((g < 2) ? (b_ih[grow] + b_hh[grow]) : b_ih[grow]) * sc;
          }
          e[j] = bfb(v);
        }
        f.i[0] = (int)(e[0] | (e[1] << 16)); f.i[1] = (int)(e[2] | (e[3] << 16));
        f.i[2] = (int)(e[4] | (e[5] << 16)); f.i[3] = (int)(e[6] | (e[7] << 16));
      }
      bgi[g] = f;
    }
    f32x4 dhwV, dhbV, bhnV;
    #pragma unroll
    for (int r = 0; r < 4; ++r) {
      dhwV[r] = -L2E * dhw[uu0 + r];
      dhbV[r] = -L2E * dhb[uu0 + r];
      bhnV[r] = b_hh[256 + uu0 + r] * (2.f * L2E);
    }

    // x̂ lanes: waves 0-3, lanes 0..23
    const int  item = wv * 24 + lane;
    const bool xl = (wv < 4) && (lane < 24);
    const int  xrow = item / 6, xch = item - 6 * (item / 6);
    float dxwS = 0.f, dxbS = 0.f, xm_l = 0.f, run = 0.f, xlast = 0.f;
    if (xl) {
      dxwS = -L2E * dxw[xch]; dxbS = -L2E * dxb[xch]; xm_l = x_mean[xch];
      if (t0 > 0) { run = runst[(b0 + xrow) * 6 + xch]; xlast = xlst[(b0 + xrow) * 6 + xch]; }
    }
    // x̂ write offset in fragment-major gin
    const int ginWo = (((2 * xch) >> 3) << 8) + xrow * 16 + ((2 * xch) & 7) * 2;

    // stagers: waves 4-7
    const bool sl = (tid >= 256) && (tid < 464);
    const int sid = tid - 256;
    const int rrow = sid / 13, rcc = sid - 13 * (sid / 13);
    const float* xbase = x + (size_t)(b0 + rrow) * (NT * 13) + rcc;

    f32x4 hn = {0.f, 0.f, 0.f, 0.f};
    if (t0 > 0) hn = *(const f32x4*)&hstate[(size_t)(b0 + lr) * NH + uu0];

    // fragment-major offsets: read = s*1024 + lane*16 (conflict-free);
    // write = (2wv+(lg>>1))*256 + lr*16 + (lg&1)*8
    const int wOff = (2 * wv + (lg >> 1)) * 256 + lr * 16 + (lg & 1) * 8;
    const int rBase = lane * 16;

    // zero both gin parity buffers (2048 B)
    ((unsigned*)ginB)[tid] = 0u;

    const int cb0 = t0 & 1;
    if (sl) {
      xw[cb0][rrow][rcc]     = xbase[(size_t)t0 * 13];
      const int t1 = (t0 + 1 < NT) ? t0 + 1 : NT - 1;
      xw[cb0 ^ 1][rrow][rcc] = xbase[(size_t)t1 * 13];
    }
    __syncthreads();

    if (tid < 32) {   // bias column k=12 -> block 1, byte 8: {1.0bf16, 0}
      const int par = tid >> 4, row = tid & 15;
      *(unsigned*)(ginB + par * 1024 + 256 + row * 16 + 8) = 0x00003F80u;
    }

    f32x4 hd;
    {
      const float dt0 = xw[cb0][lr][12];
      #pragma unroll
      for (int r = 0; r < 4; ++r)
        hd[r] = ex2(fminf(dt0 * dhwV[r] + dhbV[r], 0.f)) * hn[r];
      *(unsigned long long*)(hdL + cb0 * 4096 + wOff) = pk4(hd);
    }
    if (xl) {
      const float xv = xw[cb0][xrow][xch], mt = xw[cb0][xrow][6 + xch];
      const float dtv = xw[cb0][xrow][12];
      const bool obs = mt > 0.5f;
      run = obs ? 0.f : run + dtv;
      const float gx = ex2(fminf(run * dxwS + dxbS, 0.f));
      xlast = obs ? xv : xlast;
      const float xh = mt * xv + (1.f - mt) * (gx * xlast + (1.f - gx) * xm_l);
      *(unsigned*)(ginB + cb0 * 1024 + ginWo) = pkbf(xh, mt);
    }
    float xr2 = 0.f;
    if (sl) { const int t2 = (t0 + 2 < NT) ? t0 + 2 : NT - 1; xr2 = xbase[(size_t)t2 * 13]; }
    BAR();

    char* hwp = hcur + (((size_t)blockIdx.x * Tc) << 12) + wv * 32 + lg * 8 + lr * 256;
    const f32x4 z4 = {0.f, 0.f, 0.f, 0.f};
    const int tend = t0 + Tc;

    #pragma unroll 1
    for (int t = t0; t < tend; ++t) {
      const int p = t & 1, q = p ^ 1;

      // gamma for t+1 hoisted BEFORE MFMAs (dt staged)
      const float dtn = xw[q][lr][12];
      f32x4 gmn;
      #pragma unroll
      for (int r = 0; r < 4; ++r)
        gmn[r] = ex2(fminf(dtn * dhwV[r] + dhbV[r], 0.f));

      FRAG ag; ag.i = *(const i32x4*)(ginB + p * 1024 + rBase);
      FRAG ah[4];
      #pragma unroll
      for (int s = 0; s < 4; ++s)
        ah[s].i = *(const i32x4*)(hdL + p * 4096 + s * 1024 + rBase);

      if (sl) {
        xw[p][rrow][rcc] = xr2;
        xr2 = xbase[(size_t)((t + 3 < NT) ? t + 3 : NT - 1) * 13];
      }

      f32x4 accr = MFMA(bgi[0].b, ag.b, z4);
      f32x4 accz = MFMA(bgi[1].b, ag.b, z4);
      f32x4 ani  = MFMA(bgi[2].b, ag.b, z4);
      f32x4 anh  = z4;
      #pragma unroll
      for (int s = 0; s < 4; ++s) {
        accr = MFMA(bhh[0][s].b, ah[s].b, accr);
        accz = MFMA(bhh[1][s].b, ah[s].b, accz);
        anh  = MFMA(bhh[2][s].b, ah[s].b, anh);
      }

      // tail with paired reciprocals (20 trans/lane)
      f32x4 hbv = anh + bhnV;
      float A[4];
      #pragma unroll
      for (int r = 0; r < 4; ++r) A[r] = 1.f + ex2(accr[r]);
      const float R01 = rcp_(A[0] * A[1]);
      const float R23 = rcp_(A[2] * A[3]);
      float rr[4];
      rr[0] = A[1] * R01; rr[1] = A[0] * R01;
      rr[2] = A[3] * R23; rr[3] = A[2] * R23;

      float num[4], den[4];
      #pragma unroll
      for (int r = 0; r < 4; ++r) {
        const float na = __builtin_fmaf(rr[r], hbv[r], ani[r]);
        const float En = ex2(na);
        const float Ez = ex2(accz[r]);
        const float ep1 = En + 1.f;
        num[r] = __builtin_fmaf(hd[r], ep1, (En - 1.f) * Ez);
        den[r] = ep1 * (1.f + Ez);
      }
      const float D01 = rcp_(den[0] * den[1]);
      const float D23 = rcp_(den[2] * den[3]);
      hn[0] = num[0] * den[1] * D01; hn[1] = num[1] * den[0] * D01;
      hn[2] = num[2] * den[3] * D23; hn[3] = num[3] * den[2] * D23;

      // stream h_t (8B/lane, never drained at barrier)
      *(unsigned long long*)hwp = pk4(hn);
      hwp += 4096;

      // decay for t+1 (gamma precomputed) + fragment-major LDS write
      #pragma unroll
      for (int r = 0; r < 4; ++r) hd[r] = gmn[r] * hn[r];
      *(unsigned long long*)(hdL + q * 4096 + wOff) = pk4(hd);

      if (xl && t + 1 < tend) {
        const float xv = xw[q][xrow][xch], mt = xw[q][xrow][6 + xch];
        const float dtv = xw[q][xrow][12];
        const bool obs = mt > 0.5f;
        run = obs ? 0.f : run + dtv;
        const float gx = ex2(fminf(run * dxwS + dxbS, 0.f));
        xlast = obs ? xv : xlast;
        const float xh = mt * xv + (1.f - mt) * (gx * xlast + (1.f - gx) * xm_l);
        *(unsigned*)(ginB + q * 1024 + ginWo) = pkbf(xh, mt);
      }
      BAR();
    }

    *(f32x4*)&hstate[(size_t)(b0 + lr) * NH + uu0] = hn;
    if (xl) { runst[(b0 + xrow) * 6 + xch] = run; xlst[(b0 + xrow) * 6 + xch] = xlast; }

  } else {
    // ==================== HEAD ROLE (round-7 verbatim, dynamic base) ====================
    if (t0p < 0) return;

    const int hb = blockIdx.x - hb0;             // 0..nhb-1
    const int nhb = (int)gridDim.x - hb0;
    const int tid2 = tid & 255, half = tid >> 8; // two 4-wave halves
    const int lane2 = tid2 & 63, w4 = tid2 >> 6;
    const int lr2 = lane2 & 15, lg2 = lane2 >> 4;
    char* ldsH = lds + half * 20480;             // hs@0(8K), y1@8192(8K), u1@16384(4K)

    FRAG bw1a[4], bw1b[4], bq1[4], bw2[4], bq2[2];
    #pragma unroll
    for (int s = 0; s < 4; ++s) {
      bw1a[s] = pk8(w1 + (size_t)((2 * w4) * 16 + lr2) * 128 + 32 * s + 8 * lg2, 1.f);
      bw1b[s] = pk8(w1 + (size_t)((2 * w4 + 1) * 16 + lr2) * 128 + 32 * s + 8 * lg2, 1.f);
      bq1[s]  = pk8(wu1 + (size_t)(w4 * 16 + lr2) * 128 + 32 * s + 8 * lg2, 1.f);
      if (lr2 < 6) bw2[s] = pk8(w2 + (size_t)lr2 * 128 + 32 * s + 8 * lg2, 1.f);
      else         bw2[s].i = i32x4{0, 0, 0, 0};
      if (s < 2) {
        if (lr2 < 6) bq2[s] = pk8(wu2 + (size_t)lr2 * 64 + 32 * s + 8 * lg2, 1.f);
        else         bq2[s].i = i32x4{0, 0, 0, 0};
      }
    }
    const float b1a = b1[(2 * w4) * 16 + lr2], b1b = b1[(2 * w4 + 1) * 16 + lr2];
    const float bu1l = bu1[w4 * 16 + lr2];
    const float b2l = (lr2 < 6) ? b2[lr2] : 0.f, bu2l = (lr2 < 6) ? bu2[lr2] : 0.f;
    const f32x4 z4 = {0.f, 0.f, 0.f, 0.f};

    const int tc2 = Tc >> 1, total = 64 * tc2;
    const int cy0 = (2 * w4) * 16 + lr2, cy1 = (2 * w4 + 1) * 16 + lr2;
    const int cu = w4 * 16 + lr2;

    #pragma unroll 1
    for (int it = 0; it < niter; ++it) {
      const int hu = it * (nhb * 2) + hb * 2 + half;
      const bool valid = hu < total;
      int chain = 0, tp = 0;
      if (valid) { chain = hu / tc2; tp = hu - chain * tc2; }

      if (valid) {   // stage 2 h tiles, cell-swizzled
        const char* src = hprev + (((size_t)chain * Tc + tp * 2) << 12);
        const int o = tid2 * 16, row = o >> 8, cell = (o >> 4) & 15;
        #pragma unroll
        for (int k2 = 0; k2 < 2; ++k2) {
          uint4 v = *(const uint4*)(src + k2 * 4096 + o);
          *(uint4*)(ldsH + k2 * 4096 + row * 256 + ((cell ^ (row & 7)) << 4)) = v;
        }
      }
      __syncthreads();

      if (valid) {   // layer 1 over 2 t-tiles
        #pragma unroll
        for (int k = 0; k < 2; ++k) {
          FRAG A[4];
          #pragma unroll
          for (int s = 0; s < 4; ++s)
            A[s].i = *(const i32x4*)(ldsH + k * 4096 + lr2 * 256 +
                                     (((4 * s + lg2) ^ (lr2 & 7)) << 4));
          f32x4 aa = z4, ab = z4, au = z4;
          #pragma unroll
          for (int s = 0; s < 4; ++s) {
            aa = MFMA(A[s].b, bw1a[s].b, aa);
            ab = MFMA(A[s].b, bw1b[s].b, ab);
            au = MFMA(A[s].b, bq1[s].b, au);
          }
          #pragma unroll
          for (int r = 0; r < 4; ++r) {
            const int m = k * 16 + 4 * lg2 + r;
            *(unsigned short*)(ldsH + 8192 + m * 256 + (((cy0 >> 3) ^ (m & 7)) << 4) +
                               (cy0 & 7) * 2) = bfb(fmaxf(aa[r] + b1a, 0.f));
            *(unsigned short*)(ldsH + 8192 + m * 256 + (((cy1 >> 3) ^ (m & 7)) << 4) +
                               (cy1 & 7) * 2) = bfb(fmaxf(ab[r] + b1b, 0.f));
            *(unsigned short*)(ldsH + 16384 + m * 128 + (((cu >> 3) ^ (m & 7)) << 4) +
                               (cu & 7) * 2) = bfb(fmaxf(au[r] + bu1l, 0.f));
          }
        }
      }
      __syncthreads();

      if (valid && w4 < 2) {   // layer 2: wave w4 finishes t-tile w4
        const int mrow = w4 * 16 + lr2;
        FRAG Y[4], U[2];
        #pragma unroll
        for (int s = 0; s < 4; ++s)
          Y[s].i = *(const i32x4*)(ldsH + 8192 + mrow * 256 +
                                   (((4 * s + lg2) ^ (lr2 & 7)) << 4));
        #pragma unroll
        for (int s = 0; s < 2; ++s)
          U[s].i = *(const i32x4*)(ldsH + 16384 + mrow * 128 +
                                   (((4 * s + lg2) ^ (lr2 & 7)) << 4));
        f32x4 ap = z4, aq = z4;
        #pragma unroll
        for (int s = 0; s < 4; ++s) ap = MFMA(Y[s].b, bw2[s].b, ap);
        #pragma unroll
        for (int s = 0; s < 2; ++s) aq = MFMA(U[s].b, bq2[s].b, aq);

        if (lr2 < 6) {
          const int t = t0p + tp * 2 + w4;
          #pragma unroll
          for (int r = 0; r < 4; ++r) {
            const int b = chain * 16 + 4 * lg2 + r;
            const size_t o = ((size_t)b * NT + t) * 6 + lr2;
            out[o] = ap[r] + b2l;
            const float xa = aq[r] + bu2l;
            const float sp = fmaxf(xa, 0.f) + 0.6931471805599453f *
                __builtin_amdgcn_logf(1.f + ex2(-fabsf(xa) * L2E));
            out[(size_t)NB * NT * 6 + o] = sp;
          }
        }
      }
      __syncthreads();
    }
  }
}

extern "C" void kernel_launch(void* const* d_in, const int* in_sizes, int n_in,
                              void* d_out, int out_size, void* d_ws, size_t ws_size,
                              hipStream_t stream) {
  (void)in_sizes; (void)n_in; (void)out_size;
  const float* p[18];
  for (int i = 0; i < 18; ++i) p[i] = (const float*)d_in[i];

  const size_t STATE = (size_t)1024 * 128 * 4 + 2 * (size_t)1024 * 6 * 4;
  int Tc = 256;   // small head-tail dispatch; hws dbuf fits ws
  while (Tc > 16 && (2 * ((size_t)Tc << 18) + STATE) > ws_size) Tc >>= 1;

  char* h0 = (char*)d_ws;
  char* h1 = h0 + ((size_t)Tc << 18);
  float* hstate = (float*)(h1 + ((size_t)Tc << 18));
  float* runst = hstate + 1024 * 128;
  float* xlst = runst + 1024 * 6;

  const int nch = NT / Tc;
  const int total = 64 * (Tc / 2);

  for (int k = 0; k <= nch; ++k) {
    char* hcur = (k & 1) ? h1 : h0;
    const char* hprev = (k & 1) ? h0 : h1;
    const int t0 = k * Tc;
    const int hb0 = (t0 < NT) ? 64 : 0;
    const int stride = (256 - hb0) * 2;
    const int niter = (total + stride - 1) / stride;
    hipLaunchKernelGGL(grud_combo, dim3(256), dim3(512), 0, stream,
                       p[0], p[1], p[2], p[3], p[4], p[5], p[6], p[7], p[8], p[9],
                       p[10], p[11], p[12], p[13], p[14], p[15], p[16], p[17],
                       (float*)d_out, hcur, hprev, hstate, runst, xlst,
                       t0, (k - 1) * Tc, Tc, niter, hb0);
  }
}